// Round 1
// baseline (2451.206 us; speedup 1.0000x reference)
//
#include <hip/hip_runtime.h>

#define THREADS 256

// ---------------- CSR build ----------------

__global__ void k_count(const int* __restrict__ rows, int* __restrict__ cnt, int e) {
  int i = blockIdx.x * THREADS + threadIdx.x;
  if (i < e) atomicAdd(&cnt[rows[i]], 1);
}

// 1024 elements per block, 256 threads x 4; writes per-chunk exclusive scan into outp
__global__ void k_scan1(const int* __restrict__ cnt, int* __restrict__ outp,
                        int* __restrict__ bsum, int n) {
  __shared__ int sh[256];
  int t = threadIdx.x;
  int base = blockIdx.x * 1024 + t * 4;
  int v[4];
#pragma unroll
  for (int j = 0; j < 4; ++j) {
    int idx = base + j;
    v[j] = (idx < n) ? cnt[idx] : 0;
  }
  int tot = v[0] + v[1] + v[2] + v[3];
  sh[t] = tot;
  __syncthreads();
  for (int off = 1; off < 256; off <<= 1) {
    int x = 0;
    if (t >= off) x = sh[t - off];
    __syncthreads();
    sh[t] += x;
    __syncthreads();
  }
  if (t == 255) bsum[blockIdx.x] = sh[255];
  int run = sh[t] - tot;  // exclusive prefix of this thread within block
#pragma unroll
  for (int j = 0; j < 4; ++j) {
    int idx = base + j;
    if (idx < n) outp[idx] = run;
    run += v[j];
  }
}

// single block exclusive scan of block sums (nb <= 256)
__global__ void k_scan2(int* __restrict__ bsum, int nb) {
  __shared__ int sh[256];
  int t = threadIdx.x;
  int v = (t < nb) ? bsum[t] : 0;
  sh[t] = v;
  __syncthreads();
  for (int off = 1; off < 256; off <<= 1) {
    int x = 0;
    if (t >= off) x = sh[t - off];
    __syncthreads();
    sh[t] += x;
    __syncthreads();
  }
  if (t < nb) bsum[t] = sh[t] - v;
}

__global__ void k_scan3(int* __restrict__ rowptr, const int* __restrict__ bsum,
                        int n, int total) {
  int base = blockIdx.x * 1024 + threadIdx.x * 4;
  int add = bsum[blockIdx.x];
#pragma unroll
  for (int j = 0; j < 4; ++j) {
    int idx = base + j;
    if (idx < n) rowptr[idx] += add;
  }
  if (blockIdx.x == 0 && threadIdx.x == 0) rowptr[n] = total;
}

__global__ void k_fill(const int* __restrict__ rows, const int* __restrict__ cols,
                       const float* __restrict__ w, const int* __restrict__ rowptr,
                       int* __restrict__ fill, int* __restrict__ ocol,
                       float* __restrict__ ow, int e) {
  int i = blockIdx.x * THREADS + threadIdx.x;
  if (i >= e) return;
  int r = rows[i];
  int p = rowptr[r] + atomicAdd(&fill[r], 1);
  ocol[p] = cols[i];
  ow[p] = w[i];
}

// ---------------- GEMM: C[M,N] = A'[M,K] @ B[K,N], A' = A*scale+shift (BN fold) ----------------
// 64x64 block tile, BK=16, 256 threads, 4x4 per thread.

__global__ __launch_bounds__(256) void k_gemm(
    const float* __restrict__ A, const float* __restrict__ B, float* __restrict__ C,
    int M, int N, int K,
    const float* __restrict__ bnScale, const float* __restrict__ bnShift) {
  __shared__ float As[16][68];  // [k][row], padded for 16B alignment
  __shared__ float Bs[16][68];  // [k][col]
  int tid = threadIdx.x;
  int m0 = blockIdx.x * 64;
  int n0 = blockIdx.y * 64;
  int tx = tid & 15, ty = tid >> 4;
  int arow = tid >> 2, ak = (tid & 3) * 4;
  int brow = tid >> 4, bcol = (tid & 15) * 4;
  float acc[4][4] = {};

  for (int k0 = 0; k0 < K; k0 += 16) {
    float4 av = make_float4(0.f, 0.f, 0.f, 0.f);
    int gr = m0 + arow;
    if (gr < M) av = *(const float4*)(A + (size_t)gr * K + k0 + ak);
    if (bnScale) {
      float4 sc = *(const float4*)(bnScale + k0 + ak);
      float4 sf = *(const float4*)(bnShift + k0 + ak);
      av.x = av.x * sc.x + sf.x;
      av.y = av.y * sc.y + sf.y;
      av.z = av.z * sc.z + sf.z;
      av.w = av.w * sc.w + sf.w;
    }
    float4 bv = *(const float4*)(B + (size_t)(k0 + brow) * N + n0 + bcol);
    __syncthreads();
    As[ak + 0][arow] = av.x;
    As[ak + 1][arow] = av.y;
    As[ak + 2][arow] = av.z;
    As[ak + 3][arow] = av.w;
    *(float4*)&Bs[brow][bcol] = bv;
    __syncthreads();
#pragma unroll
    for (int kk = 0; kk < 16; ++kk) {
      float4 a4 = *(const float4*)&As[kk][ty * 4];
      float4 b4 = *(const float4*)&Bs[kk][tx * 4];
      float a[4] = {a4.x, a4.y, a4.z, a4.w};
      float b[4] = {b4.x, b4.y, b4.z, b4.w};
#pragma unroll
      for (int i = 0; i < 4; ++i)
#pragma unroll
        for (int j = 0; j < 4; ++j) acc[i][j] += a[i] * b[j];
    }
  }

#pragma unroll
  for (int i = 0; i < 4; ++i) {
    int gr = m0 + ty * 4 + i;
    if (gr < M) {
      float4 o = make_float4(acc[i][0], acc[i][1], acc[i][2], acc[i][3]);
      *(float4*)(C + (size_t)gr * N + n0 + tx * 4) = o;
    }
  }
}

// ---------------- Aggregation: out[r] = relu(bias + sum_e w[e]*sup[col[e]]) ----------------
// one wave per row

template <int D>
__global__ __launch_bounds__(256) void k_agg(
    const float* __restrict__ sup, const int* __restrict__ rowptr,
    const int* __restrict__ cols, const float* __restrict__ w,
    const float* __restrict__ bias, float* __restrict__ out, int n) {
  int wid = (blockIdx.x * THREADS + threadIdx.x) >> 6;
  int lane = threadIdx.x & 63;
  if (wid >= n) return;
  int p0 = rowptr[wid], p1 = rowptr[wid + 1];
  if constexpr (D == 256) {
    const float4* supv = (const float4*)sup;
    float4 acc = make_float4(0.f, 0.f, 0.f, 0.f);
    for (int p = p0; p < p1; ++p) {
      int c = cols[p];
      float wt = w[p];
      float4 v = supv[(size_t)c * 64 + lane];
      acc.x += wt * v.x;
      acc.y += wt * v.y;
      acc.z += wt * v.z;
      acc.w += wt * v.w;
    }
    float4 b = *(const float4*)(bias + lane * 4);
    float4 r;
    r.x = fmaxf(acc.x + b.x, 0.f);
    r.y = fmaxf(acc.y + b.y, 0.f);
    r.z = fmaxf(acc.z + b.z, 0.f);
    r.w = fmaxf(acc.w + b.w, 0.f);
    *(float4*)(out + (size_t)wid * 256 + lane * 4) = r;
  } else {  // D == 64
    float acc = 0.f;
    for (int p = p0; p < p1; ++p) acc += w[p] * sup[(size_t)cols[p] * 64 + lane];
    out[(size_t)wid * 64 + lane] = fmaxf(acc + bias[lane], 0.f);
  }
}

// ---------------- BN stats ----------------

__global__ void k_colstats(const float* __restrict__ y, float* __restrict__ sums, int n) {
  int c = threadIdx.x;  // 256 columns
  int r0 = blockIdx.x * 512;
  int r1 = min(r0 + 512, n);
  float s = 0.f, s2 = 0.f;
  for (int r = r0; r < r1; ++r) {
    float v = y[(size_t)r * 256 + c];
    s += v;
    s2 += v * v;
  }
  atomicAdd(&sums[c], s);
  atomicAdd(&sums[256 + c], s2);
}

__global__ void k_bnparam(const float* __restrict__ sums, float* __restrict__ scale,
                          float* __restrict__ shift, int n) {
  int c = threadIdx.x;
  float inv = 1.0f / (float)n;
  float mean = sums[c] * inv;
  float var = sums[256 + c] * inv - mean * mean;
  float rstd = rsqrtf(var + 1e-5f);
  scale[c] = rstd;
  shift[c] = -mean * rstd;
}

// ---------------- launch ----------------

extern "C" void kernel_launch(void* const* d_in, const int* in_sizes, int n_in,
                              void* d_out, int out_size, void* d_ws, size_t ws_size,
                              hipStream_t stream) {
  const float* x = (const float*)d_in[0];
  const int* ei = (const int*)d_in[1];      // [2, E]
  const float* ew = (const float*)d_in[2];  // [E]
  const float* W1 = (const float*)d_in[3];
  const float* b1 = (const float*)d_in[4];
  const float* W2 = (const float*)d_in[5];
  const float* b2 = (const float*)d_in[6];
  const float* W3 = (const float*)d_in[7];
  const float* b3 = (const float*)d_in[8];
  float* out = (float*)d_out;

  const int N = in_sizes[0] / 512;  // 100000
  const int E = in_sizes[2];        // 3200000

  // workspace bump allocator (256B aligned)
  char* p = (char*)d_ws;
  auto alloc = [&](size_t bytes) {
    void* r = (void*)p;
    p += (bytes + 255) & ~(size_t)255;
    return r;
  };
  int* rowptr = (int*)alloc((size_t)(N + 1) * 4);
  int* cnt = (int*)alloc((size_t)N * 4);
  int* bsum = (int*)alloc(4096);
  float* sums = (float*)alloc(512 * 4);
  float* scale = (float*)alloc(256 * 4);
  float* shift = (float*)alloc(256 * 4);
  int* ccol = (int*)alloc((size_t)E * 4);
  float* cw = (float*)alloc((size_t)E * 4);
  float* bufA = (float*)alloc((size_t)N * 256 * 4);
  float* bufB = (float*)alloc((size_t)N * 256 * 4);

  const int* rows = ei;
  const int* colsIn = ei + E;

  // --- CSR build ---
  hipMemsetAsync(cnt, 0, (size_t)N * 4, stream);
  k_count<<<(E + THREADS - 1) / THREADS, THREADS, 0, stream>>>(rows, cnt, E);
  int nb = (N + 1023) / 1024;
  k_scan1<<<nb, 256, 0, stream>>>(cnt, rowptr, bsum, N);
  k_scan2<<<1, 256, 0, stream>>>(bsum, nb);
  k_scan3<<<nb, 256, 0, stream>>>(rowptr, bsum, N, E);
  hipMemsetAsync(cnt, 0, (size_t)N * 4, stream);
  k_fill<<<(E + THREADS - 1) / THREADS, THREADS, 0, stream>>>(
      rows, colsIn, ew, rowptr, cnt, ccol, cw, E);

  int aggBlocks = (N * 64 + THREADS - 1) / THREADS;
  dim3 g256((N + 63) / 64, 4);
  dim3 g64((N + 63) / 64, 1);

  // --- Layer 1: support = x @ W1 ; y1 = relu(agg + b1) ; BN stats ---
  k_gemm<<<g256, 256, 0, stream>>>(x, W1, bufA, N, 256, 512, nullptr, nullptr);
  k_agg<256><<<aggBlocks, THREADS, 0, stream>>>(bufA, rowptr, ccol, cw, b1, bufB, N);
  hipMemsetAsync(sums, 0, 512 * 4, stream);
  k_colstats<<<(N + 511) / 512, 256, 0, stream>>>(bufB, sums, N);
  k_bnparam<<<1, 256, 0, stream>>>(sums, scale, shift, N);

  // --- Layer 2: support = BN(y1) @ W2 ; y2 = relu(agg + b2) ; BN stats ---
  k_gemm<<<g256, 256, 0, stream>>>(bufB, W2, bufA, N, 256, 256, scale, shift);
  k_agg<256><<<aggBlocks, THREADS, 0, stream>>>(bufA, rowptr, ccol, cw, b2, bufB, N);
  hipMemsetAsync(sums, 0, 512 * 4, stream);
  k_colstats<<<(N + 511) / 512, 256, 0, stream>>>(bufB, sums, N);
  k_bnparam<<<1, 256, 0, stream>>>(sums, scale, shift, N);

  // --- Layer 3: support = BN(y2) @ W3 ; out = relu(agg + b3) ---
  k_gemm<<<g64, 256, 0, stream>>>(bufB, W3, bufA, N, 64, 256, scale, shift);
  k_agg<64><<<aggBlocks, THREADS, 0, stream>>>(bufA, rowptr, ccol, cw, b3, out, N);
}

// Round 2
// 1701.162 us; speedup vs baseline: 1.4409x; 1.4409x over previous
//
#include <hip/hip_runtime.h>

#define THREADS 256

typedef _Float16 f16;
typedef _Float16 f16x8 __attribute__((ext_vector_type(8)));
typedef _Float16 f16x4 __attribute__((ext_vector_type(4)));
typedef float f32x4 __attribute__((ext_vector_type(4)));

// ---------------- CSR build ----------------

__global__ void k_count(const int* __restrict__ rows, int* __restrict__ cnt, int e) {
  int i = blockIdx.x * THREADS + threadIdx.x;
  if (i < e) atomicAdd(&cnt[rows[i]], 1);
}

__global__ void k_scan1(const int* __restrict__ cnt, int* __restrict__ outp,
                        int* __restrict__ bsum, int n) {
  __shared__ int sh[256];
  int t = threadIdx.x;
  int base = blockIdx.x * 1024 + t * 4;
  int v[4];
#pragma unroll
  for (int j = 0; j < 4; ++j) {
    int idx = base + j;
    v[j] = (idx < n) ? cnt[idx] : 0;
  }
  int tot = v[0] + v[1] + v[2] + v[3];
  sh[t] = tot;
  __syncthreads();
  for (int off = 1; off < 256; off <<= 1) {
    int x = 0;
    if (t >= off) x = sh[t - off];
    __syncthreads();
    sh[t] += x;
    __syncthreads();
  }
  if (t == 255) bsum[blockIdx.x] = sh[255];
  int run = sh[t] - tot;
#pragma unroll
  for (int j = 0; j < 4; ++j) {
    int idx = base + j;
    if (idx < n) outp[idx] = run;
    run += v[j];
  }
}

__global__ void k_scan2(int* __restrict__ bsum, int nb) {
  __shared__ int sh[256];
  int t = threadIdx.x;
  int v = (t < nb) ? bsum[t] : 0;
  sh[t] = v;
  __syncthreads();
  for (int off = 1; off < 256; off <<= 1) {
    int x = 0;
    if (t >= off) x = sh[t - off];
    __syncthreads();
    sh[t] += x;
    __syncthreads();
  }
  if (t < nb) bsum[t] = sh[t] - v;
}

__global__ void k_scan3(int* __restrict__ rowptr, const int* __restrict__ bsum,
                        int n, int total) {
  int base = blockIdx.x * 1024 + threadIdx.x * 4;
  int add = bsum[blockIdx.x];
#pragma unroll
  for (int j = 0; j < 4; ++j) {
    int idx = base + j;
    if (idx < n) rowptr[idx] += add;
  }
  if (blockIdx.x == 0 && threadIdx.x == 0) rowptr[n] = total;
}

__global__ void k_fill(const int* __restrict__ rows, const int* __restrict__ cols,
                       const float* __restrict__ w, const int* __restrict__ rowptr,
                       int* __restrict__ fill, int* __restrict__ ocol,
                       float* __restrict__ ow, int e) {
  int i = blockIdx.x * THREADS + threadIdx.x;
  if (i >= e) return;
  int r = rows[i];
  int p = rowptr[r] + atomicAdd(&fill[r], 1);
  ocol[p] = cols[i];
  ow[p] = w[i];
}

// ---------------- W convert+transpose: Wt[n][k] = (f16) W[k][n] ----------------

__global__ void k_convW(const float* __restrict__ W, f16* __restrict__ Wt, int K, int N) {
  int i = blockIdx.x * THREADS + threadIdx.x;  // over N*K outputs
  if (i >= N * K) return;
  int n = i / K, k = i - n * K;
  Wt[i] = (f16)W[(size_t)k * N + n];
}

// ---------------- MFMA GEMM: Csup[M][BN] = (A*scale+shift)[M][K] @ Wt^T, f16 in, f16 out ----
// BN = full N (256 or 64). Grid.x over M/64. 4 waves.
// BN==256: wave w owns rows 0..63, cols [w*64, w*64+64)  (WM=4, WN=4)
// BN==64 : wave w owns rows [w*16, w*16+16), cols 0..63   (WM=1, WN=4)

template <int BN>
__global__ __launch_bounds__(256) void k_gemm_mfma(
    const float* __restrict__ A, const f16* __restrict__ Wt, f16* __restrict__ Csup,
    int M, int K, const float* __restrict__ bnScale, const float* __restrict__ bnShift) {
  constexpr int BK = 32;
  constexpr int LDT = BK + 8;  // 80B row stride: 16B aligned, 2-way bank alias (free)
  __shared__ __align__(16) f16 As[64][LDT];
  __shared__ __align__(16) f16 Bs[BN][LDT];

  const int tid = threadIdx.x;
  const int wave = tid >> 6;
  const int lane = tid & 63;
  const int m0 = blockIdx.x * 64;
  constexpr int WM = (BN == 256) ? 4 : 1;
  constexpr int WN = 4;
  const int wrow = (BN == 256) ? 0 : wave * 16;
  const int wcol = (BN == 256) ? wave * 64 : 0;
  const int l15 = lane & 15;
  const int lq = lane >> 4;

  const int srow = tid >> 2;          // 0..63
  const int skofs = (tid & 3) * 8;    // 0,8,16,24
  constexpr int BROWS = BN / 64;      // Wt rows handled per thread

  f32x4 acc[WM][WN] = {};

  for (int k0 = 0; k0 < K; k0 += BK) {
    // ---- load staging data to registers (before barrier) ----
    float va[8];
    int gr = m0 + srow;
    if (gr < M) {
      const float* ap = A + (size_t)gr * K + k0 + skofs;
      *(float4*)&va[0] = *(const float4*)ap;
      *(float4*)&va[4] = *(const float4*)(ap + 4);
    } else {
#pragma unroll
      for (int j = 0; j < 8; ++j) va[j] = 0.f;
    }
    if (bnScale) {
      float sc[8], sf[8];
      *(float4*)&sc[0] = *(const float4*)(bnScale + k0 + skofs);
      *(float4*)&sc[4] = *(const float4*)(bnScale + k0 + skofs + 4);
      *(float4*)&sf[0] = *(const float4*)(bnShift + k0 + skofs);
      *(float4*)&sf[4] = *(const float4*)(bnShift + k0 + skofs + 4);
#pragma unroll
      for (int j = 0; j < 8; ++j) va[j] = va[j] * sc[j] + sf[j];
    }
    f16x8 a16;
#pragma unroll
    for (int j = 0; j < 8; ++j) a16[j] = (f16)va[j];

    f16x8 vb[BROWS];
#pragma unroll
    for (int j = 0; j < BROWS; ++j)
      vb[j] = *(const f16x8*)(Wt + (size_t)(srow + j * 64) * K + k0 + skofs);

    __syncthreads();  // previous iteration's LDS reads complete
    *(f16x8*)&As[srow][skofs] = a16;
#pragma unroll
    for (int j = 0; j < BROWS; ++j) *(f16x8*)&Bs[srow + j * 64][skofs] = vb[j];
    __syncthreads();

    // ---- fragments + MFMA ----
    f16x8 af[WM], bf[WN];
#pragma unroll
    for (int m = 0; m < WM; ++m)
      af[m] = *(const f16x8*)&As[wrow + m * 16 + l15][lq * 8];
#pragma unroll
    for (int n = 0; n < WN; ++n)
      bf[n] = *(const f16x8*)&Bs[wcol + n * 16 + l15][lq * 8];
#pragma unroll
    for (int m = 0; m < WM; ++m)
#pragma unroll
      for (int n = 0; n < WN; ++n)
        acc[m][n] = __builtin_amdgcn_mfma_f32_16x16x32_f16(af[m], bf[n], acc[m][n], 0, 0, 0);
  }

  // ---- store f16 support ----
#pragma unroll
  for (int m = 0; m < WM; ++m) {
#pragma unroll
    for (int r = 0; r < 4; ++r) {
      int row = m0 + wrow + m * 16 + lq * 4 + r;
      if (row < M) {
        f16* cp = Csup + (size_t)row * BN + wcol + l15;
#pragma unroll
        for (int n = 0; n < WN; ++n) cp[n * 16] = (f16)acc[m][n][r];
      }
    }
  }
}

// ---------------- Aggregation: out[r] = relu(bias + sum_e w[e]*sup[col[e]]) ----------------
// one wave per row; sup is f16

template <int D>
__global__ __launch_bounds__(256) void k_agg(
    const f16* __restrict__ sup, const int* __restrict__ rowptr,
    const int* __restrict__ cols, const float* __restrict__ w,
    const float* __restrict__ bias, float* __restrict__ out, int n) {
  int wid = (blockIdx.x * THREADS + threadIdx.x) >> 6;
  int lane = threadIdx.x & 63;
  if (wid >= n) return;
  int p0 = rowptr[wid], p1 = rowptr[wid + 1];
  if constexpr (D == 256) {
    const f16x4* supv = (const f16x4*)sup;  // 4 f16 per lane, 64 lanes = 256
    float acc0 = 0.f, acc1 = 0.f, acc2 = 0.f, acc3 = 0.f;
    for (int p = p0; p < p1; ++p) {
      int c = cols[p];
      float wt = w[p];
      f16x4 v = supv[(size_t)c * 64 + lane];
      acc0 += wt * (float)v[0];
      acc1 += wt * (float)v[1];
      acc2 += wt * (float)v[2];
      acc3 += wt * (float)v[3];
    }
    float4 b = *(const float4*)(bias + lane * 4);
    float4 r;
    r.x = fmaxf(acc0 + b.x, 0.f);
    r.y = fmaxf(acc1 + b.y, 0.f);
    r.z = fmaxf(acc2 + b.z, 0.f);
    r.w = fmaxf(acc3 + b.w, 0.f);
    *(float4*)(out + (size_t)wid * 256 + lane * 4) = r;
  } else {  // D == 64, one f16 per lane
    float acc = 0.f;
    for (int p = p0; p < p1; ++p) acc += w[p] * (float)sup[(size_t)cols[p] * 64 + lane];
    out[(size_t)wid * 64 + lane] = fmaxf(acc + bias[lane], 0.f);
  }
}

// ---------------- BN stats ----------------

__global__ void k_colstats(const float* __restrict__ y, float* __restrict__ sums, int n) {
  int c = threadIdx.x;  // 256 columns
  int r0 = blockIdx.x * 512;
  int r1 = min(r0 + 512, n);
  float s = 0.f, s2 = 0.f;
  for (int r = r0; r < r1; ++r) {
    float v = y[(size_t)r * 256 + c];
    s += v;
    s2 += v * v;
  }
  atomicAdd(&sums[c], s);
  atomicAdd(&sums[256 + c], s2);
}

__global__ void k_bnparam(const float* __restrict__ sums, float* __restrict__ scale,
                          float* __restrict__ shift, int n) {
  int c = threadIdx.x;
  float inv = 1.0f / (float)n;
  float mean = sums[c] * inv;
  float var = sums[256 + c] * inv - mean * mean;
  float rstd = rsqrtf(var + 1e-5f);
  scale[c] = rstd;
  shift[c] = -mean * rstd;
}

// ---------------- launch ----------------

extern "C" void kernel_launch(void* const* d_in, const int* in_sizes, int n_in,
                              void* d_out, int out_size, void* d_ws, size_t ws_size,
                              hipStream_t stream) {
  const float* x = (const float*)d_in[0];
  const int* ei = (const int*)d_in[1];
  const float* ew = (const float*)d_in[2];
  const float* W1 = (const float*)d_in[3];
  const float* b1 = (const float*)d_in[4];
  const float* W2 = (const float*)d_in[5];
  const float* b2 = (const float*)d_in[6];
  const float* W3 = (const float*)d_in[7];
  const float* b3 = (const float*)d_in[8];
  float* out = (float*)d_out;

  const int N = in_sizes[0] / 512;  // 100000
  const int E = in_sizes[2];        // 3200000

  char* p = (char*)d_ws;
  auto alloc = [&](size_t bytes) {
    void* r = (void*)p;
    p += (bytes + 255) & ~(size_t)255;
    return r;
  };
  int* rowptr = (int*)alloc((size_t)(N + 1) * 4);
  int* cnt = (int*)alloc((size_t)N * 4);
  int* bsum = (int*)alloc(4096);
  float* sums = (float*)alloc(512 * 4);
  float* scale = (float*)alloc(256 * 4);
  float* shift = (float*)alloc(256 * 4);
  f16* Wt1 = (f16*)alloc((size_t)512 * 256 * 2);
  f16* Wt2 = (f16*)alloc((size_t)256 * 256 * 2);
  f16* Wt3 = (f16*)alloc((size_t)256 * 64 * 2);
  int* ccol = (int*)alloc((size_t)E * 4);
  float* cw = (float*)alloc((size_t)E * 4);
  f16* sup = (f16*)alloc((size_t)N * 256 * 2);
  float* act = (float*)alloc((size_t)N * 256 * 4);

  const int* rows = ei;
  const int* colsIn = ei + E;

  // --- CSR build ---
  hipMemsetAsync(cnt, 0, (size_t)N * 4, stream);
  k_count<<<(E + THREADS - 1) / THREADS, THREADS, 0, stream>>>(rows, cnt, E);
  int nb = (N + 1023) / 1024;
  k_scan1<<<nb, 256, 0, stream>>>(cnt, rowptr, bsum, N);
  k_scan2<<<1, 256, 0, stream>>>(bsum, nb);
  k_scan3<<<nb, 256, 0, stream>>>(rowptr, bsum, N, E);
  hipMemsetAsync(cnt, 0, (size_t)N * 4, stream);
  k_fill<<<(E + THREADS - 1) / THREADS, THREADS, 0, stream>>>(
      rows, colsIn, ew, rowptr, cnt, ccol, cw, E);

  // --- weight convert/transpose ---
  k_convW<<<(512 * 256 + THREADS - 1) / THREADS, THREADS, 0, stream>>>(W1, Wt1, 512, 256);
  k_convW<<<(256 * 256 + THREADS - 1) / THREADS, THREADS, 0, stream>>>(W2, Wt2, 256, 256);
  k_convW<<<(256 * 64 + THREADS - 1) / THREADS, THREADS, 0, stream>>>(W3, Wt3, 256, 64);

  const int gemmBlocks = (N + 63) / 64;
  const int aggBlocks = (N * 64 + THREADS - 1) / THREADS;

  // --- Layer 1 ---
  k_gemm_mfma<256><<<gemmBlocks, 256, 0, stream>>>(x, Wt1, sup, N, 512, nullptr, nullptr);
  k_agg<256><<<aggBlocks, THREADS, 0, stream>>>(sup, rowptr, ccol, cw, b1, act, N);
  hipMemsetAsync(sums, 0, 512 * 4, stream);
  k_colstats<<<(N + 511) / 512, 256, 0, stream>>>(act, sums, N);
  k_bnparam<<<1, 256, 0, stream>>>(sums, scale, shift, N);

  // --- Layer 2 ---
  k_gemm_mfma<256><<<gemmBlocks, 256, 0, stream>>>(act, Wt2, sup, N, 256, scale, shift);
  k_agg<256><<<aggBlocks, THREADS, 0, stream>>>(sup, rowptr, ccol, cw, b2, act, N);
  hipMemsetAsync(sums, 0, 512 * 4, stream);
  k_colstats<<<(N + 511) / 512, 256, 0, stream>>>(act, sums, N);
  k_bnparam<<<1, 256, 0, stream>>>(sums, scale, shift, N);

  // --- Layer 3 ---
  k_gemm_mfma<64><<<gemmBlocks, 256, 0, stream>>>(act, Wt3, sup, N, 256, scale, shift);
  k_agg<64><<<aggBlocks, THREADS, 0, stream>>>(sup, rowptr, ccol, cw, b3, out, N);
}

// Round 3
// 1276.105 us; speedup vs baseline: 1.9208x; 1.3331x over previous
//
#include <hip/hip_runtime.h>

#define THREADS 256

typedef _Float16 f16;
typedef _Float16 f16x8 __attribute__((ext_vector_type(8)));
typedef _Float16 f16x4 __attribute__((ext_vector_type(4)));
typedef float f32x4 __attribute__((ext_vector_type(4)));

// ---------------- CSR build ----------------

__global__ void k_count(const int* __restrict__ rows, int* __restrict__ cnt, int e) {
  int i = blockIdx.x * THREADS + threadIdx.x;
  if (i < e) atomicAdd(&cnt[rows[i]], 1);
}

__global__ void k_scan1(const int* __restrict__ cnt, int* __restrict__ outp,
                        int* __restrict__ bsum, int n) {
  __shared__ int sh[256];
  int t = threadIdx.x;
  int base = blockIdx.x * 1024 + t * 4;
  int v[4];
#pragma unroll
  for (int j = 0; j < 4; ++j) {
    int idx = base + j;
    v[j] = (idx < n) ? cnt[idx] : 0;
  }
  int tot = v[0] + v[1] + v[2] + v[3];
  sh[t] = tot;
  __syncthreads();
  for (int off = 1; off < 256; off <<= 1) {
    int x = 0;
    if (t >= off) x = sh[t - off];
    __syncthreads();
    sh[t] += x;
    __syncthreads();
  }
  if (t == 255) bsum[blockIdx.x] = sh[255];
  int run = sh[t] - tot;
#pragma unroll
  for (int j = 0; j < 4; ++j) {
    int idx = base + j;
    if (idx < n) outp[idx] = run;
    run += v[j];
  }
}

__global__ void k_scan2(int* __restrict__ bsum, int nb) {
  __shared__ int sh[256];
  int t = threadIdx.x;
  int v = (t < nb) ? bsum[t] : 0;
  sh[t] = v;
  __syncthreads();
  for (int off = 1; off < 256; off <<= 1) {
    int x = 0;
    if (t >= off) x = sh[t - off];
    __syncthreads();
    sh[t] += x;
    __syncthreads();
  }
  if (t < nb) bsum[t] = sh[t] - v;
}

__global__ void k_scan3(int* __restrict__ rowptr, const int* __restrict__ bsum,
                        int n, int total) {
  int base = blockIdx.x * 1024 + threadIdx.x * 4;
  int add = bsum[blockIdx.x];
#pragma unroll
  for (int j = 0; j < 4; ++j) {
    int idx = base + j;
    if (idx < n) rowptr[idx] += add;
  }
  if (blockIdx.x == 0 && threadIdx.x == 0) rowptr[n] = total;
}

// packed edge: .x = col, .y = bit-cast weight
__global__ void k_fill(const int* __restrict__ rows, const int* __restrict__ cols,
                       const float* __restrict__ w, const int* __restrict__ rowptr,
                       int* __restrict__ fill, int2* __restrict__ ed, int e) {
  int i = blockIdx.x * THREADS + threadIdx.x;
  if (i >= e) return;
  int r = rows[i];
  int p = rowptr[r] + atomicAdd(&fill[r], 1);
  ed[p] = make_int2(cols[i], __float_as_int(w[i]));
}

// ---------------- W convert+transpose: Wt[n][k] = (f16) W[k][n] ----------------

__global__ void k_convW(const float* __restrict__ W, f16* __restrict__ Wt, int K, int N) {
  int i = blockIdx.x * THREADS + threadIdx.x;
  if (i >= N * K) return;
  int n = i / K, k = i - n * K;
  Wt[i] = (f16)W[(size_t)k * N + n];
}

// ---------------- MFMA GEMM (unchanged from round 2) ----------------

template <int BN>
__global__ __launch_bounds__(256) void k_gemm_mfma(
    const float* __restrict__ A, const f16* __restrict__ Wt, f16* __restrict__ Csup,
    int M, int K, const float* __restrict__ bnScale, const float* __restrict__ bnShift) {
  constexpr int BK = 32;
  constexpr int LDT = BK + 8;
  __shared__ __align__(16) f16 As[64][LDT];
  __shared__ __align__(16) f16 Bs[BN][LDT];

  const int tid = threadIdx.x;
  const int wave = tid >> 6;
  const int lane = tid & 63;
  const int m0 = blockIdx.x * 64;
  constexpr int WM = (BN == 256) ? 4 : 1;
  constexpr int WN = 4;
  const int wrow = (BN == 256) ? 0 : wave * 16;
  const int wcol = (BN == 256) ? wave * 64 : 0;
  const int l15 = lane & 15;
  const int lq = lane >> 4;

  const int srow = tid >> 2;
  const int skofs = (tid & 3) * 8;
  constexpr int BROWS = BN / 64;

  f32x4 acc[WM][WN] = {};

  for (int k0 = 0; k0 < K; k0 += BK) {
    float va[8];
    int gr = m0 + srow;
    if (gr < M) {
      const float* ap = A + (size_t)gr * K + k0 + skofs;
      *(float4*)&va[0] = *(const float4*)ap;
      *(float4*)&va[4] = *(const float4*)(ap + 4);
    } else {
#pragma unroll
      for (int j = 0; j < 8; ++j) va[j] = 0.f;
    }
    if (bnScale) {
      float sc[8], sf[8];
      *(float4*)&sc[0] = *(const float4*)(bnScale + k0 + skofs);
      *(float4*)&sc[4] = *(const float4*)(bnScale + k0 + skofs + 4);
      *(float4*)&sf[0] = *(const float4*)(bnShift + k0 + skofs);
      *(float4*)&sf[4] = *(const float4*)(bnShift + k0 + skofs + 4);
#pragma unroll
      for (int j = 0; j < 8; ++j) va[j] = va[j] * sc[j] + sf[j];
    }
    f16x8 a16;
#pragma unroll
    for (int j = 0; j < 8; ++j) a16[j] = (f16)va[j];

    f16x8 vb[BROWS];
#pragma unroll
    for (int j = 0; j < BROWS; ++j)
      vb[j] = *(const f16x8*)(Wt + (size_t)(srow + j * 64) * K + k0 + skofs);

    __syncthreads();
    *(f16x8*)&As[srow][skofs] = a16;
#pragma unroll
    for (int j = 0; j < BROWS; ++j) *(f16x8*)&Bs[srow + j * 64][skofs] = vb[j];
    __syncthreads();

    f16x8 af[WM], bf[WN];
#pragma unroll
    for (int m = 0; m < WM; ++m)
      af[m] = *(const f16x8*)&As[wrow + m * 16 + l15][lq * 8];
#pragma unroll
    for (int n = 0; n < WN; ++n)
      bf[n] = *(const f16x8*)&Bs[wcol + n * 16 + l15][lq * 8];
#pragma unroll
    for (int m = 0; m < WM; ++m)
#pragma unroll
      for (int n = 0; n < WN; ++n)
        acc[m][n] = __builtin_amdgcn_mfma_f32_16x16x32_f16(af[m], bf[n], acc[m][n], 0, 0, 0);
  }

#pragma unroll
  for (int m = 0; m < WM; ++m) {
#pragma unroll
    for (int r = 0; r < 4; ++r) {
      int row = m0 + wrow + m * 16 + lq * 4 + r;
      if (row < M) {
        f16* cp = Csup + (size_t)row * BN + wcol + l15;
#pragma unroll
        for (int n = 0; n < WN; ++n) cp[n * 16] = (f16)acc[m][n][r];
      }
    }
  }
}

// ---------------- Aggregation: out[r] = relu(bias + sum_e w[e]*sup[col[e]]) ----------------
// one wave per row; 8-deep gather pipeline for memory-level parallelism

template <int D>
__global__ __launch_bounds__(256) void k_agg(
    const f16* __restrict__ sup, const int* __restrict__ rowptr,
    const int2* __restrict__ ed, const float* __restrict__ bias,
    float* __restrict__ out, int n) {
  int wid = (blockIdx.x * THREADS + threadIdx.x) >> 6;
  int lane = threadIdx.x & 63;
  if (wid >= n) return;
  int p0 = rowptr[wid], p1 = rowptr[wid + 1];

  if constexpr (D == 256) {
    const f16x4* supv = (const f16x4*)sup;
    float acc[4][4] = {};
    int p = p0;
    for (; p + 8 <= p1; p += 8) {
      int2 e[8];
#pragma unroll
      for (int j = 0; j < 8; ++j) e[j] = ed[p + j];
      f16x4 v[8];
#pragma unroll
      for (int j = 0; j < 8; ++j) v[j] = supv[(size_t)e[j].x * 64 + lane];
#pragma unroll
      for (int j = 0; j < 8; ++j) {
        float wt = __int_as_float(e[j].y);
        acc[j & 3][0] += wt * (float)v[j][0];
        acc[j & 3][1] += wt * (float)v[j][1];
        acc[j & 3][2] += wt * (float)v[j][2];
        acc[j & 3][3] += wt * (float)v[j][3];
      }
    }
    for (; p < p1; ++p) {
      int2 e0 = ed[p];
      float wt = __int_as_float(e0.y);
      f16x4 v = supv[(size_t)e0.x * 64 + lane];
      acc[0][0] += wt * (float)v[0];
      acc[0][1] += wt * (float)v[1];
      acc[0][2] += wt * (float)v[2];
      acc[0][3] += wt * (float)v[3];
    }
    float4 b = *(const float4*)(bias + lane * 4);
    float4 r;
    r.x = fmaxf(acc[0][0] + acc[1][0] + acc[2][0] + acc[3][0] + b.x, 0.f);
    r.y = fmaxf(acc[0][1] + acc[1][1] + acc[2][1] + acc[3][1] + b.y, 0.f);
    r.z = fmaxf(acc[0][2] + acc[1][2] + acc[2][2] + acc[3][2] + b.z, 0.f);
    r.w = fmaxf(acc[0][3] + acc[1][3] + acc[2][3] + acc[3][3] + b.w, 0.f);
    *(float4*)(out + (size_t)wid * 256 + lane * 4) = r;
  } else {  // D == 64
    float acc[4] = {};
    int p = p0;
    for (; p + 8 <= p1; p += 8) {
      int2 e[8];
#pragma unroll
      for (int j = 0; j < 8; ++j) e[j] = ed[p + j];
      f16 v[8];
#pragma unroll
      for (int j = 0; j < 8; ++j) v[j] = sup[(size_t)e[j].x * 64 + lane];
#pragma unroll
      for (int j = 0; j < 8; ++j)
        acc[j & 3] += __int_as_float(e[j].y) * (float)v[j];
    }
    for (; p < p1; ++p) {
      int2 e0 = ed[p];
      acc[0] += __int_as_float(e0.y) * (float)sup[(size_t)e0.x * 64 + lane];
    }
    out[(size_t)wid * 64 + lane] =
        fmaxf(acc[0] + acc[1] + acc[2] + acc[3] + bias[lane], 0.f);
  }
}

// ---------------- BN stats ----------------

__global__ void k_colstats(const float* __restrict__ y, float* __restrict__ sums, int n) {
  int c = threadIdx.x;
  int r0 = blockIdx.x * 512;
  int r1 = min(r0 + 512, n);
  float s = 0.f, s2 = 0.f;
  for (int r = r0; r < r1; ++r) {
    float v = y[(size_t)r * 256 + c];
    s += v;
    s2 += v * v;
  }
  atomicAdd(&sums[c], s);
  atomicAdd(&sums[256 + c], s2);
}

__global__ void k_bnparam(const float* __restrict__ sums, float* __restrict__ scale,
                          float* __restrict__ shift, int n) {
  int c = threadIdx.x;
  float inv = 1.0f / (float)n;
  float mean = sums[c] * inv;
  float var = sums[256 + c] * inv - mean * mean;
  float rstd = rsqrtf(var + 1e-5f);
  scale[c] = rstd;
  shift[c] = -mean * rstd;
}

// ---------------- launch ----------------

extern "C" void kernel_launch(void* const* d_in, const int* in_sizes, int n_in,
                              void* d_out, int out_size, void* d_ws, size_t ws_size,
                              hipStream_t stream) {
  const float* x = (const float*)d_in[0];
  const int* ei = (const int*)d_in[1];
  const float* ew = (const float*)d_in[2];
  const float* W1 = (const float*)d_in[3];
  const float* b1 = (const float*)d_in[4];
  const float* W2 = (const float*)d_in[5];
  const float* b2 = (const float*)d_in[6];
  const float* W3 = (const float*)d_in[7];
  const float* b3 = (const float*)d_in[8];
  float* out = (float*)d_out;

  const int N = in_sizes[0] / 512;  // 100000
  const int E = in_sizes[2];        // 3200000

  char* p = (char*)d_ws;
  auto alloc = [&](size_t bytes) {
    void* r = (void*)p;
    p += (bytes + 255) & ~(size_t)255;
    return r;
  };
  int* rowptr = (int*)alloc((size_t)(N + 1) * 4);
  int* cnt = (int*)alloc((size_t)N * 4);
  int* bsum = (int*)alloc(4096);
  float* sums = (float*)alloc(512 * 4);
  float* scale = (float*)alloc(256 * 4);
  float* shift = (float*)alloc(256 * 4);
  f16* Wt1 = (f16*)alloc((size_t)512 * 256 * 2);
  f16* Wt2 = (f16*)alloc((size_t)256 * 256 * 2);
  f16* Wt3 = (f16*)alloc((size_t)256 * 64 * 2);
  int2* ed = (int2*)alloc((size_t)E * 8);
  f16* sup = (f16*)alloc((size_t)N * 256 * 2);
  float* act = (float*)alloc((size_t)N * 256 * 4);

  const int* rows = ei;
  const int* colsIn = ei + E;

  // --- CSR build ---
  hipMemsetAsync(cnt, 0, (size_t)N * 4, stream);
  k_count<<<(E + THREADS - 1) / THREADS, THREADS, 0, stream>>>(rows, cnt, E);
  int nb = (N + 1023) / 1024;
  k_scan1<<<nb, 256, 0, stream>>>(cnt, rowptr, bsum, N);
  k_scan2<<<1, 256, 0, stream>>>(bsum, nb);
  k_scan3<<<nb, 256, 0, stream>>>(rowptr, bsum, N, E);
  hipMemsetAsync(cnt, 0, (size_t)N * 4, stream);
  k_fill<<<(E + THREADS - 1) / THREADS, THREADS, 0, stream>>>(
      rows, colsIn, ew, rowptr, cnt, ed, E);

  // --- weight convert/transpose ---
  k_convW<<<(512 * 256 + THREADS - 1) / THREADS, THREADS, 0, stream>>>(W1, Wt1, 512, 256);
  k_convW<<<(256 * 256 + THREADS - 1) / THREADS, THREADS, 0, stream>>>(W2, Wt2, 256, 256);
  k_convW<<<(256 * 64 + THREADS - 1) / THREADS, THREADS, 0, stream>>>(W3, Wt3, 256, 64);

  const int gemmBlocks = (N + 63) / 64;
  const int aggBlocks = (N * 64 + THREADS - 1) / THREADS;

  // --- Layer 1 ---
  k_gemm_mfma<256><<<gemmBlocks, 256, 0, stream>>>(x, Wt1, sup, N, 512, nullptr, nullptr);
  k_agg<256><<<aggBlocks, THREADS, 0, stream>>>(sup, rowptr, ed, b1, act, N);
  hipMemsetAsync(sums, 0, 512 * 4, stream);
  k_colstats<<<(N + 511) / 512, 256, 0, stream>>>(act, sums, N);
  k_bnparam<<<1, 256, 0, stream>>>(sums, scale, shift, N);

  // --- Layer 2 ---
  k_gemm_mfma<256><<<gemmBlocks, 256, 0, stream>>>(act, Wt2, sup, N, 256, scale, shift);
  k_agg<256><<<aggBlocks, THREADS, 0, stream>>>(sup, rowptr, ed, b2, act, N);
  hipMemsetAsync(sums, 0, 512 * 4, stream);
  k_colstats<<<(N + 511) / 512, 256, 0, stream>>>(act, sums, N);
  k_bnparam<<<1, 256, 0, stream>>>(sums, scale, shift, N);

  // --- Layer 3 ---
  k_gemm_mfma<64><<<gemmBlocks, 256, 0, stream>>>(act, Wt3, sup, N, 256, scale, shift);
  k_agg<64><<<aggBlocks, THREADS, 0, stream>>>(sup, rowptr, ed, b3, out, N);
}

// Round 4
// 1223.611 us; speedup vs baseline: 2.0033x; 1.0429x over previous
//
#include <hip/hip_runtime.h>

#define THREADS 256

typedef _Float16 f16;
typedef _Float16 f16x8 __attribute__((ext_vector_type(8)));
typedef _Float16 f16x4 __attribute__((ext_vector_type(4)));
typedef float f32x4 __attribute__((ext_vector_type(4)));

// ---------------- CSR build ----------------

__global__ void k_count(const int* __restrict__ rows, int* __restrict__ cnt, int e) {
  int i = blockIdx.x * THREADS + threadIdx.x;
  if (i < e) atomicAdd(&cnt[rows[i]], 1);
}

__global__ void k_scan1(const int* __restrict__ cnt, int* __restrict__ outp,
                        int* __restrict__ bsum, int n) {
  __shared__ int sh[256];
  int t = threadIdx.x;
  int base = blockIdx.x * 1024 + t * 4;
  int v[4];
#pragma unroll
  for (int j = 0; j < 4; ++j) {
    int idx = base + j;
    v[j] = (idx < n) ? cnt[idx] : 0;
  }
  int tot = v[0] + v[1] + v[2] + v[3];
  sh[t] = tot;
  __syncthreads();
  for (int off = 1; off < 256; off <<= 1) {
    int x = 0;
    if (t >= off) x = sh[t - off];
    __syncthreads();
    sh[t] += x;
    __syncthreads();
  }
  if (t == 255) bsum[blockIdx.x] = sh[255];
  int run = sh[t] - tot;
#pragma unroll
  for (int j = 0; j < 4; ++j) {
    int idx = base + j;
    if (idx < n) outp[idx] = run;
    run += v[j];
  }
}

__global__ void k_scan2(int* __restrict__ bsum, int nb) {
  __shared__ int sh[256];
  int t = threadIdx.x;
  int v = (t < nb) ? bsum[t] : 0;
  sh[t] = v;
  __syncthreads();
  for (int off = 1; off < 256; off <<= 1) {
    int x = 0;
    if (t >= off) x = sh[t - off];
    __syncthreads();
    sh[t] += x;
    __syncthreads();
  }
  if (t < nb) bsum[t] = sh[t] - v;
}

__global__ void k_scan3(int* __restrict__ rowptr, const int* __restrict__ bsum,
                        int n, int total) {
  int base = blockIdx.x * 1024 + threadIdx.x * 4;
  int add = bsum[blockIdx.x];
#pragma unroll
  for (int j = 0; j < 4; ++j) {
    int idx = base + j;
    if (idx < n) rowptr[idx] += add;
  }
  if (blockIdx.x == 0 && threadIdx.x == 0) rowptr[n] = total;
}

// packed edge: .x = col, .y = bit-cast weight
__global__ void k_fill(const int* __restrict__ rows, const int* __restrict__ cols,
                       const float* __restrict__ w, const int* __restrict__ rowptr,
                       int* __restrict__ fill, int2* __restrict__ ed, int e) {
  int i = blockIdx.x * THREADS + threadIdx.x;
  if (i >= e) return;
  int r = rows[i];
  int p = rowptr[r] + atomicAdd(&fill[r], 1);
  ed[p] = make_int2(cols[i], __float_as_int(w[i]));
}

// ---------------- weight prep ----------------

// Wt[n][k] = (f16) W[k][n]   (layer 1, no BN)
__global__ void k_convW(const float* __restrict__ W, f16* __restrict__ Wt, int K, int N) {
  int i = blockIdx.x * THREADS + threadIdx.x;
  if (i >= N * K) return;
  int n = i / K, k = i - n * K;
  Wt[i] = (f16)W[(size_t)k * N + n];
}

// Wt'[n][k] = (f16)(sc[k] * W[k][n])   (BN scale folded)
__global__ void k_convWs(const float* __restrict__ W, const float* __restrict__ sc,
                         f16* __restrict__ Wt, int K, int N) {
  int i = blockIdx.x * THREADS + threadIdx.x;
  if (i >= N * K) return;
  int n = i / K, k = i - n * K;
  Wt[i] = (f16)(sc[k] * W[(size_t)k * N + n]);
}

// bias'[n] += sum over 16 k's of sf[k]*W[k][n]; grid = K/16 blocks, 256 threads
__global__ void k_biasfold(const float* __restrict__ sf, const float* __restrict__ W,
                           float* __restrict__ biasRow, int K, int N) {
  int n = threadIdx.x;
  if (n >= N) return;
  int k0 = blockIdx.x * 16;
  float s = 0.f;
#pragma unroll
  for (int i = 0; i < 16; ++i) {
    int k = k0 + i;
    s += sf[k] * W[(size_t)k * N + n];
  }
  atomicAdd(&biasRow[n], s);
}

// ---------------- MFMA GEMM: Csup[M][BN] = A[M][K] @ Wt^T + biasRow, f16 out ----
// AF16: A is f16 (act); else fp32 (x). biasRow nullable.

template <int BN, bool AF16>
__global__ __launch_bounds__(256) void k_gemm_mfma(
    const void* __restrict__ Ap, const f16* __restrict__ Wt,
    const float* __restrict__ biasRow, f16* __restrict__ Csup, int M, int K) {
  constexpr int BK = 32;
  constexpr int LDT = BK + 8;
  __shared__ __align__(16) f16 As[64][LDT];
  __shared__ __align__(16) f16 Bs[BN][LDT];

  const int tid = threadIdx.x;
  const int wave = tid >> 6;
  const int lane = tid & 63;
  const int m0 = blockIdx.x * 64;
  constexpr int WM = (BN == 256) ? 4 : 1;
  constexpr int WN = 4;
  const int wrow = (BN == 256) ? 0 : wave * 16;
  const int wcol = (BN == 256) ? wave * 64 : 0;
  const int l15 = lane & 15;
  const int lq = lane >> 4;

  const int srow = tid >> 2;
  const int skofs = (tid & 3) * 8;
  constexpr int BROWS = BN / 64;

  f32x4 acc[WM][WN] = {};

  for (int k0 = 0; k0 < K; k0 += BK) {
    f16x8 a16;
    int gr = m0 + srow;
    if constexpr (AF16) {
      if (gr < M) {
        a16 = *(const f16x8*)((const f16*)Ap + (size_t)gr * K + k0 + skofs);
      } else {
#pragma unroll
        for (int j = 0; j < 8; ++j) a16[j] = (f16)0.f;
      }
    } else {
      float va[8];
      if (gr < M) {
        const float* ap = (const float*)Ap + (size_t)gr * K + k0 + skofs;
        *(float4*)&va[0] = *(const float4*)ap;
        *(float4*)&va[4] = *(const float4*)(ap + 4);
      } else {
#pragma unroll
        for (int j = 0; j < 8; ++j) va[j] = 0.f;
      }
#pragma unroll
      for (int j = 0; j < 8; ++j) a16[j] = (f16)va[j];
    }

    f16x8 vb[BROWS];
#pragma unroll
    for (int j = 0; j < BROWS; ++j)
      vb[j] = *(const f16x8*)(Wt + (size_t)(srow + j * 64) * K + k0 + skofs);

    __syncthreads();
    *(f16x8*)&As[srow][skofs] = a16;
#pragma unroll
    for (int j = 0; j < BROWS; ++j) *(f16x8*)&Bs[srow + j * 64][skofs] = vb[j];
    __syncthreads();

    f16x8 af[WM], bf[WN];
#pragma unroll
    for (int m = 0; m < WM; ++m)
      af[m] = *(const f16x8*)&As[wrow + m * 16 + l15][lq * 8];
#pragma unroll
    for (int n = 0; n < WN; ++n)
      bf[n] = *(const f16x8*)&Bs[wcol + n * 16 + l15][lq * 8];
#pragma unroll
    for (int m = 0; m < WM; ++m)
#pragma unroll
      for (int n = 0; n < WN; ++n)
        acc[m][n] = __builtin_amdgcn_mfma_f32_16x16x32_f16(af[m], bf[n], acc[m][n], 0, 0, 0);
  }

  float bb[WN];
#pragma unroll
  for (int n = 0; n < WN; ++n)
    bb[n] = biasRow ? biasRow[wcol + n * 16 + l15] : 0.f;

#pragma unroll
  for (int m = 0; m < WM; ++m) {
#pragma unroll
    for (int r = 0; r < 4; ++r) {
      int row = m0 + wrow + m * 16 + lq * 4 + r;
      if (row < M) {
        f16* cp = Csup + (size_t)row * BN + wcol + l15;
#pragma unroll
        for (int n = 0; n < WN; ++n) cp[n * 16] = (f16)(acc[m][n][r] + bb[n]);
      }
    }
  }
}

// ---------------- Aggregation D=256: one wave per row, f16 in, f16 out ----------------

__global__ __launch_bounds__(256) void k_agg256(
    const f16* __restrict__ sup, const int* __restrict__ rowptr,
    const int2* __restrict__ ed, const float* __restrict__ bias,
    f16* __restrict__ out, int n) {
  int wid = (blockIdx.x * THREADS + threadIdx.x) >> 6;
  int lane = threadIdx.x & 63;
  if (wid >= n) return;
  int p0 = rowptr[wid], p1 = rowptr[wid + 1];

  const f16x4* supv = (const f16x4*)sup;
  float acc[4][4] = {};
  int p = p0;
  for (; p + 8 <= p1; p += 8) {
    int2 e[8];
#pragma unroll
    for (int j = 0; j < 8; ++j) e[j] = ed[p + j];
    f16x4 v[8];
#pragma unroll
    for (int j = 0; j < 8; ++j) v[j] = supv[(size_t)e[j].x * 64 + lane];
#pragma unroll
    for (int j = 0; j < 8; ++j) {
      float wt = __int_as_float(e[j].y);
      acc[j & 3][0] += wt * (float)v[j][0];
      acc[j & 3][1] += wt * (float)v[j][1];
      acc[j & 3][2] += wt * (float)v[j][2];
      acc[j & 3][3] += wt * (float)v[j][3];
    }
  }
  for (; p < p1; ++p) {
    int2 e0 = ed[p];
    float wt = __int_as_float(e0.y);
    f16x4 v = supv[(size_t)e0.x * 64 + lane];
    acc[0][0] += wt * (float)v[0];
    acc[0][1] += wt * (float)v[1];
    acc[0][2] += wt * (float)v[2];
    acc[0][3] += wt * (float)v[3];
  }
  float4 b = *(const float4*)(bias + lane * 4);
  f16x4 r;
  r[0] = (f16)fmaxf(acc[0][0] + acc[1][0] + acc[2][0] + acc[3][0] + b.x, 0.f);
  r[1] = (f16)fmaxf(acc[0][1] + acc[1][1] + acc[2][1] + acc[3][1] + b.y, 0.f);
  r[2] = (f16)fmaxf(acc[0][2] + acc[1][2] + acc[2][2] + acc[3][2] + b.z, 0.f);
  r[3] = (f16)fmaxf(acc[0][3] + acc[1][3] + acc[2][3] + acc[3][3] + b.w, 0.f);
  *(f16x4*)(out + (size_t)wid * 256 + lane * 4) = r;
}

// ---------------- Aggregation D=64: FOUR rows per wave (16 lanes each), fp32 out ----

__global__ __launch_bounds__(256) void k_agg64(
    const f16* __restrict__ sup, const int* __restrict__ rowptr,
    const int2* __restrict__ ed, const float* __restrict__ bias,
    float* __restrict__ out, int n) {
  int gw = (blockIdx.x * THREADS + threadIdx.x) >> 6;  // wave id
  int lane = threadIdx.x & 63;
  int sub = lane >> 4;      // row within wave
  int l = lane & 15;        // feature chunk (4 f16)
  int r = gw * 4 + sub;
  if (r >= n) return;
  int p0 = rowptr[r], p1 = rowptr[r + 1];

  const f16x4* supv = (const f16x4*)sup;  // 16 chunks per 64-wide row
  float acc[2][4] = {};
  int p = p0;
  for (; p + 8 <= p1; p += 8) {
    int2 e[8];
#pragma unroll
    for (int j = 0; j < 8; ++j) e[j] = ed[p + j];
    f16x4 v[8];
#pragma unroll
    for (int j = 0; j < 8; ++j) v[j] = supv[(size_t)e[j].x * 16 + l];
#pragma unroll
    for (int j = 0; j < 8; ++j) {
      float wt = __int_as_float(e[j].y);
      acc[j & 1][0] += wt * (float)v[j][0];
      acc[j & 1][1] += wt * (float)v[j][1];
      acc[j & 1][2] += wt * (float)v[j][2];
      acc[j & 1][3] += wt * (float)v[j][3];
    }
  }
  for (; p < p1; ++p) {
    int2 e0 = ed[p];
    float wt = __int_as_float(e0.y);
    f16x4 v = supv[(size_t)e0.x * 16 + l];
    acc[0][0] += wt * (float)v[0];
    acc[0][1] += wt * (float)v[1];
    acc[0][2] += wt * (float)v[2];
    acc[0][3] += wt * (float)v[3];
  }
  float4 b = *(const float4*)(bias + l * 4);
  float4 res;
  res.x = fmaxf(acc[0][0] + acc[1][0] + b.x, 0.f);
  res.y = fmaxf(acc[0][1] + acc[1][1] + b.y, 0.f);
  res.z = fmaxf(acc[0][2] + acc[1][2] + b.z, 0.f);
  res.w = fmaxf(acc[0][3] + acc[1][3] + b.w, 0.f);
  *(float4*)(out + (size_t)r * 64 + l * 4) = res;
}

// ---------------- BN stats (f16 input) ----------------

__global__ void k_colstats(const f16* __restrict__ y, float* __restrict__ sums, int n) {
  int c = threadIdx.x;
  int r0 = blockIdx.x * 512;
  int r1 = min(r0 + 512, n);
  float s = 0.f, s2 = 0.f;
  for (int r = r0; r < r1; ++r) {
    float v = (float)y[(size_t)r * 256 + c];
    s += v;
    s2 += v * v;
  }
  atomicAdd(&sums[c], s);
  atomicAdd(&sums[256 + c], s2);
}

__global__ void k_bnparam(const float* __restrict__ sums, float* __restrict__ scale,
                          float* __restrict__ shift, int n) {
  int c = threadIdx.x;
  float inv = 1.0f / (float)n;
  float mean = sums[c] * inv;
  float var = sums[256 + c] * inv - mean * mean;
  float rstd = rsqrtf(var + 1e-5f);
  scale[c] = rstd;
  shift[c] = -mean * rstd;
}

// ---------------- launch ----------------

extern "C" void kernel_launch(void* const* d_in, const int* in_sizes, int n_in,
                              void* d_out, int out_size, void* d_ws, size_t ws_size,
                              hipStream_t stream) {
  const float* x = (const float*)d_in[0];
  const int* ei = (const int*)d_in[1];
  const float* ew = (const float*)d_in[2];
  const float* W1 = (const float*)d_in[3];
  const float* b1 = (const float*)d_in[4];
  const float* W2 = (const float*)d_in[5];
  const float* b2 = (const float*)d_in[6];
  const float* W3 = (const float*)d_in[7];
  const float* b3 = (const float*)d_in[8];
  float* out = (float*)d_out;

  const int N = in_sizes[0] / 512;  // 100000
  const int E = in_sizes[2];        // 3200000

  char* p = (char*)d_ws;
  auto alloc = [&](size_t bytes) {
    void* r = (void*)p;
    p += (bytes + 255) & ~(size_t)255;
    return r;
  };
  int* rowptr = (int*)alloc((size_t)(N + 1) * 4);
  int* cnt = (int*)alloc((size_t)N * 4);
  int* bsum = (int*)alloc(4096);
  float* sums = (float*)alloc(512 * 4);
  float* scale = (float*)alloc(256 * 4);
  float* shift = (float*)alloc(256 * 4);
  float* biasRow = (float*)alloc(256 * 4);
  f16* Wt1 = (f16*)alloc((size_t)512 * 256 * 2);
  f16* Wt2 = (f16*)alloc((size_t)256 * 256 * 2);
  f16* Wt3 = (f16*)alloc((size_t)256 * 64 * 2);
  int2* ed = (int2*)alloc((size_t)E * 8);
  f16* sup = (f16*)alloc((size_t)N * 256 * 2);
  f16* act = (f16*)alloc((size_t)N * 256 * 2);

  const int* rows = ei;
  const int* colsIn = ei + E;

  // --- CSR build ---
  hipMemsetAsync(cnt, 0, (size_t)N * 4, stream);
  k_count<<<(E + THREADS - 1) / THREADS, THREADS, 0, stream>>>(rows, cnt, E);
  int nb = (N + 1023) / 1024;
  k_scan1<<<nb, 256, 0, stream>>>(cnt, rowptr, bsum, N);
  k_scan2<<<1, 256, 0, stream>>>(bsum, nb);
  k_scan3<<<nb, 256, 0, stream>>>(rowptr, bsum, N, E);
  hipMemsetAsync(cnt, 0, (size_t)N * 4, stream);
  k_fill<<<(E + THREADS - 1) / THREADS, THREADS, 0, stream>>>(
      rows, colsIn, ew, rowptr, cnt, ed, E);

  const int gemmBlocks = (N + 63) / 64;
  const int agg256Blocks = (N * 64 + THREADS - 1) / THREADS;
  const int agg64Blocks = (((N + 3) / 4) * 64 + THREADS - 1) / THREADS;

  // --- Layer 1: no BN on input ---
  k_convW<<<(512 * 256 + THREADS - 1) / THREADS, THREADS, 0, stream>>>(W1, Wt1, 512, 256);
  k_gemm_mfma<256, false><<<gemmBlocks, 256, 0, stream>>>(x, Wt1, nullptr, sup, N, 512);
  k_agg256<<<agg256Blocks, THREADS, 0, stream>>>(sup, rowptr, ed, b1, act, N);

  // --- BN1 + fold into W2 ---
  hipMemsetAsync(sums, 0, 512 * 4, stream);
  k_colstats<<<(N + 511) / 512, 256, 0, stream>>>(act, sums, N);
  k_bnparam<<<1, 256, 0, stream>>>(sums, scale, shift, N);
  hipMemsetAsync(biasRow, 0, 256 * 4, stream);
  k_biasfold<<<16, 256, 0, stream>>>(shift, W2, biasRow, 256, 256);
  k_convWs<<<(256 * 256 + THREADS - 1) / THREADS, THREADS, 0, stream>>>(W2, scale, Wt2, 256, 256);

  // --- Layer 2 ---
  k_gemm_mfma<256, true><<<gemmBlocks, 256, 0, stream>>>(act, Wt2, biasRow, sup, N, 256);
  k_agg256<<<agg256Blocks, THREADS, 0, stream>>>(sup, rowptr, ed, b2, act, N);

  // --- BN2 + fold into W3 ---
  hipMemsetAsync(sums, 0, 512 * 4, stream);
  k_colstats<<<(N + 511) / 512, 256, 0, stream>>>(act, sums, N);
  k_bnparam<<<1, 256, 0, stream>>>(sums, scale, shift, N);
  hipMemsetAsync(biasRow, 0, 256 * 4, stream);
  k_biasfold<<<16, 256, 0, stream>>>(shift, W3, biasRow, 256, 64);
  k_convWs<<<(256 * 64 + THREADS - 1) / THREADS, THREADS, 0, stream>>>(W3, scale, Wt3, 256, 64);

  // --- Layer 3 ---
  k_gemm_mfma<64, true><<<gemmBlocks, 256, 0, stream>>>(act, Wt3, biasRow, sup, N, 256);
  k_agg64<<<agg64Blocks, THREADS, 0, stream>>>(sup, rowptr, ed, b3, out, N);
}

// Round 5
// 1083.763 us; speedup vs baseline: 2.2618x; 1.1290x over previous
//
#include <hip/hip_runtime.h>

#define THREADS 256

typedef _Float16 f16;
typedef _Float16 f16x8 __attribute__((ext_vector_type(8)));
typedef _Float16 f16x4 __attribute__((ext_vector_type(4)));
typedef float f32x4 __attribute__((ext_vector_type(4)));

// ---------------- CSR build ----------------

__global__ void k_count(const int* __restrict__ rows, int* __restrict__ cnt, int e) {
  int i = blockIdx.x * THREADS + threadIdx.x;
  if (i < e) atomicAdd(&cnt[rows[i]], 1);
}

__global__ void k_scan1(const int* __restrict__ cnt, int* __restrict__ outp,
                        int* __restrict__ bsum, int n) {
  __shared__ int sh[256];
  int t = threadIdx.x;
  int base = blockIdx.x * 1024 + t * 4;
  int v[4];
#pragma unroll
  for (int j = 0; j < 4; ++j) {
    int idx = base + j;
    v[j] = (idx < n) ? cnt[idx] : 0;
  }
  int tot = v[0] + v[1] + v[2] + v[3];
  sh[t] = tot;
  __syncthreads();
  for (int off = 1; off < 256; off <<= 1) {
    int x = 0;
    if (t >= off) x = sh[t - off];
    __syncthreads();
    sh[t] += x;
    __syncthreads();
  }
  if (t == 255) bsum[blockIdx.x] = sh[255];
  int run = sh[t] - tot;
#pragma unroll
  for (int j = 0; j < 4; ++j) {
    int idx = base + j;
    if (idx < n) outp[idx] = run;
    run += v[j];
  }
}

__global__ void k_scan2(int* __restrict__ bsum, int nb) {
  __shared__ int sh[256];
  int t = threadIdx.x;
  int v = (t < nb) ? bsum[t] : 0;
  sh[t] = v;
  __syncthreads();
  for (int off = 1; off < 256; off <<= 1) {
    int x = 0;
    if (t >= off) x = sh[t - off];
    __syncthreads();
    sh[t] += x;
    __syncthreads();
  }
  if (t < nb) bsum[t] = sh[t] - v;
}

__global__ void k_scan3(int* __restrict__ rowptr, const int* __restrict__ bsum,
                        int n, int total) {
  int base = blockIdx.x * 1024 + threadIdx.x * 4;
  int add = bsum[blockIdx.x];
#pragma unroll
  for (int j = 0; j < 4; ++j) {
    int idx = base + j;
    if (idx < n) rowptr[idx] += add;
  }
  if (blockIdx.x == 0 && threadIdx.x == 0) rowptr[n] = total;
}

// packed edge: .x = col, .y = bit-cast weight
__global__ void k_fill(const int* __restrict__ rows, const int* __restrict__ cols,
                       const float* __restrict__ w, const int* __restrict__ rowptr,
                       int* __restrict__ fill, int2* __restrict__ ed, int e) {
  int i = blockIdx.x * THREADS + threadIdx.x;
  if (i >= e) return;
  int r = rows[i];
  int p = rowptr[r] + atomicAdd(&fill[r], 1);
  ed[p] = make_int2(cols[i], __float_as_int(w[i]));
}

// ---------------- weight prep ----------------

// Wt[n][k] = (f16) W[k][n]   (layer 1, no BN); also zeroes sums
__global__ void k_convW(const float* __restrict__ W, f16* __restrict__ Wt, int K, int N,
                        float* __restrict__ sums) {
  int i = blockIdx.x * THREADS + threadIdx.x;
  if (blockIdx.x == 0 && threadIdx.x < 256) {
    sums[threadIdx.x] = 0.f;
    sums[256 + threadIdx.x] = 0.f;
  }
  if (i >= N * K) return;
  int n = i / K, k = i - n * K;
  Wt[i] = (f16)W[(size_t)k * N + n];
}

// Wt'[n][k] = (f16)(sc[k] * W[k][n])   (BN scale folded); also zeroes sums
__global__ void k_convWs(const float* __restrict__ W, const float* __restrict__ sc,
                         f16* __restrict__ Wt, int K, int N, float* __restrict__ sums) {
  int i = blockIdx.x * THREADS + threadIdx.x;
  if (blockIdx.x == 0 && threadIdx.x < 256) {
    sums[threadIdx.x] = 0.f;
    sums[256 + threadIdx.x] = 0.f;
  }
  if (i >= N * K) return;
  int n = i / K, k = i - n * K;
  Wt[i] = (f16)(sc[k] * W[(size_t)k * N + n]);
}

// bias'[n] += sum over 16 k's of sf[k]*W[k][n]; grid = K/16 blocks, 256 threads
__global__ void k_biasfold(const float* __restrict__ sf, const float* __restrict__ W,
                           float* __restrict__ biasRow, int K, int N) {
  int n = threadIdx.x;
  if (n >= N) return;
  int k0 = blockIdx.x * 16;
  float s = 0.f;
#pragma unroll
  for (int i = 0; i < 16; ++i) {
    int k = k0 + i;
    s += sf[k] * W[(size_t)k * N + n];
  }
  atomicAdd(&biasRow[n], s);
}

// ---------------- MFMA GEMM: Csup[M][BN] = A[M][K] @ Wt^T + biasRow, f16 out ----
// BM=128 rows per block, 256 threads (4 waves).
// BN==256: each wave owns all 128 rows x its 64-col strip (WM=8, WN=4)
// BN==64 : wave w owns rows [w*32, w*32+32) x all 64 cols   (WM=2, WN=4)

template <int BN, bool AF16>
__global__ __launch_bounds__(256) void k_gemm_mfma(
    const void* __restrict__ Ap, const f16* __restrict__ Wt,
    const float* __restrict__ biasRow, f16* __restrict__ Csup, int M, int K) {
  constexpr int BM = 128;
  constexpr int BK = 32;
  constexpr int LDT = BK + 8;  // 80B row stride: 16B-aligned, 2-way bank alias (free)
  __shared__ __align__(16) f16 As[BM][LDT];
  __shared__ __align__(16) f16 Bs[BN][LDT];

  const int tid = threadIdx.x;
  const int wave = tid >> 6;
  const int lane = tid & 63;
  const int m0 = blockIdx.x * BM;
  constexpr int WM = (BN == 256) ? 8 : 2;
  constexpr int WN = 4;
  const int wrow = (BN == 256) ? 0 : wave * 32;
  const int wcol = (BN == 256) ? wave * 64 : 0;
  const int l15 = lane & 15;
  const int lq = lane >> 4;

  // A staging: 2 threads per row, 16 k each
  const int arow = tid >> 1;           // 0..127
  const int akofs = (tid & 1) * 16;    // 0 or 16
  // B staging: srow 0..63, 8 k each, BROWS row-groups
  const int srow = tid >> 2;
  const int skofs = (tid & 3) * 8;
  constexpr int BROWS = BN / 64;

  f32x4 acc[WM][WN] = {};

  for (int k0 = 0; k0 < K; k0 += BK) {
    f16x8 a16[2];
    int gr = m0 + arow;
    if constexpr (AF16) {
      if (gr < M) {
        const f16* ap = (const f16*)Ap + (size_t)gr * K + k0 + akofs;
        a16[0] = *(const f16x8*)ap;
        a16[1] = *(const f16x8*)(ap + 8);
      } else {
#pragma unroll
        for (int j = 0; j < 8; ++j) { a16[0][j] = (f16)0.f; a16[1][j] = (f16)0.f; }
      }
    } else {
      float va[16];
      if (gr < M) {
        const float* ap = (const float*)Ap + (size_t)gr * K + k0 + akofs;
#pragma unroll
        for (int q = 0; q < 4; ++q) *(float4*)&va[q * 4] = *(const float4*)(ap + q * 4);
      } else {
#pragma unroll
        for (int j = 0; j < 16; ++j) va[j] = 0.f;
      }
#pragma unroll
      for (int j = 0; j < 8; ++j) { a16[0][j] = (f16)va[j]; a16[1][j] = (f16)va[8 + j]; }
    }

    f16x8 vb[BROWS];
#pragma unroll
    for (int j = 0; j < BROWS; ++j)
      vb[j] = *(const f16x8*)(Wt + (size_t)(srow + j * 64) * K + k0 + skofs);

    __syncthreads();
    *(f16x8*)&As[arow][akofs] = a16[0];
    *(f16x8*)&As[arow][akofs + 8] = a16[1];
#pragma unroll
    for (int j = 0; j < BROWS; ++j) *(f16x8*)&Bs[srow + j * 64][skofs] = vb[j];
    __syncthreads();

    f16x8 af[WM], bf[WN];
#pragma unroll
    for (int m = 0; m < WM; ++m)
      af[m] = *(const f16x8*)&As[wrow + m * 16 + l15][lq * 8];
#pragma unroll
    for (int n = 0; n < WN; ++n)
      bf[n] = *(const f16x8*)&Bs[wcol + n * 16 + l15][lq * 8];
#pragma unroll
    for (int m = 0; m < WM; ++m)
#pragma unroll
      for (int n = 0; n < WN; ++n)
        acc[m][n] = __builtin_amdgcn_mfma_f32_16x16x32_f16(af[m], bf[n], acc[m][n], 0, 0, 0);
  }

  float bb[WN];
#pragma unroll
  for (int n = 0; n < WN; ++n)
    bb[n] = biasRow ? biasRow[wcol + n * 16 + l15] : 0.f;

#pragma unroll
  for (int m = 0; m < WM; ++m) {
#pragma unroll
    for (int r = 0; r < 4; ++r) {
      int row = m0 + wrow + m * 16 + lq * 4 + r;
      if (row < M) {
        f16* cp = Csup + (size_t)row * BN + wcol + l15;
#pragma unroll
        for (int n = 0; n < WN; ++n) cp[n * 16] = (f16)(acc[m][n][r] + bb[n]);
      }
    }
  }
}

// ---------------- Aggregation D=256: one wave per row, f16 in, f16 out ----------------

__global__ __launch_bounds__(256) void k_agg256(
    const f16* __restrict__ sup, const int* __restrict__ rowptr,
    const int2* __restrict__ ed, const float* __restrict__ bias,
    f16* __restrict__ out, int n) {
  int wid = (blockIdx.x * THREADS + threadIdx.x) >> 6;
  int lane = threadIdx.x & 63;
  if (wid >= n) return;
  int p0 = rowptr[wid], p1 = rowptr[wid + 1];

  const f16x4* supv = (const f16x4*)sup;
  float acc[4][4] = {};
  int p = p0;
  for (; p + 8 <= p1; p += 8) {
    int2 e[8];
#pragma unroll
    for (int j = 0; j < 8; ++j) e[j] = ed[p + j];
    f16x4 v[8];
#pragma unroll
    for (int j = 0; j < 8; ++j) v[j] = supv[(size_t)e[j].x * 64 + lane];
#pragma unroll
    for (int j = 0; j < 8; ++j) {
      float wt = __int_as_float(e[j].y);
      acc[j & 3][0] += wt * (float)v[j][0];
      acc[j & 3][1] += wt * (float)v[j][1];
      acc[j & 3][2] += wt * (float)v[j][2];
      acc[j & 3][3] += wt * (float)v[j][3];
    }
  }
  for (; p < p1; ++p) {
    int2 e0 = ed[p];
    float wt = __int_as_float(e0.y);
    f16x4 v = supv[(size_t)e0.x * 64 + lane];
    acc[0][0] += wt * (float)v[0];
    acc[0][1] += wt * (float)v[1];
    acc[0][2] += wt * (float)v[2];
    acc[0][3] += wt * (float)v[3];
  }
  float4 b = *(const float4*)(bias + lane * 4);
  f16x4 r;
  r[0] = (f16)fmaxf(acc[0][0] + acc[1][0] + acc[2][0] + acc[3][0] + b.x, 0.f);
  r[1] = (f16)fmaxf(acc[0][1] + acc[1][1] + acc[2][1] + acc[3][1] + b.y, 0.f);
  r[2] = (f16)fmaxf(acc[0][2] + acc[1][2] + acc[2][2] + acc[3][2] + b.z, 0.f);
  r[3] = (f16)fmaxf(acc[0][3] + acc[1][3] + acc[2][3] + acc[3][3] + b.w, 0.f);
  *(f16x4*)(out + (size_t)wid * 256 + lane * 4) = r;
}

// ---------------- Aggregation D=64: FOUR rows per wave (16 lanes each), fp32 out ----

__global__ __launch_bounds__(256) void k_agg64(
    const f16* __restrict__ sup, const int* __restrict__ rowptr,
    const int2* __restrict__ ed, const float* __restrict__ bias,
    float* __restrict__ out, int n) {
  int gw = (blockIdx.x * THREADS + threadIdx.x) >> 6;
  int lane = threadIdx.x & 63;
  int sub = lane >> 4;
  int l = lane & 15;
  int r = gw * 4 + sub;
  if (r >= n) return;
  int p0 = rowptr[r], p1 = rowptr[r + 1];

  const f16x4* supv = (const f16x4*)sup;
  float acc[2][4] = {};
  int p = p0;
  for (; p + 8 <= p1; p += 8) {
    int2 e[8];
#pragma unroll
    for (int j = 0; j < 8; ++j) e[j] = ed[p + j];
    f16x4 v[8];
#pragma unroll
    for (int j = 0; j < 8; ++j) v[j] = supv[(size_t)e[j].x * 16 + l];
#pragma unroll
    for (int j = 0; j < 8; ++j) {
      float wt = __int_as_float(e[j].y);
      acc[j & 1][0] += wt * (float)v[j][0];
      acc[j & 1][1] += wt * (float)v[j][1];
      acc[j & 1][2] += wt * (float)v[j][2];
      acc[j & 1][3] += wt * (float)v[j][3];
    }
  }
  for (; p < p1; ++p) {
    int2 e0 = ed[p];
    float wt = __int_as_float(e0.y);
    f16x4 v = supv[(size_t)e0.x * 16 + l];
    acc[0][0] += wt * (float)v[0];
    acc[0][1] += wt * (float)v[1];
    acc[0][2] += wt * (float)v[2];
    acc[0][3] += wt * (float)v[3];
  }
  float4 b = *(const float4*)(bias + l * 4);
  float4 res;
  res.x = fmaxf(acc[0][0] + acc[1][0] + b.x, 0.f);
  res.y = fmaxf(acc[0][1] + acc[1][1] + b.y, 0.f);
  res.z = fmaxf(acc[0][2] + acc[1][2] + b.z, 0.f);
  res.w = fmaxf(acc[0][3] + acc[1][3] + b.w, 0.f);
  *(float4*)(out + (size_t)r * 64 + l * 4) = res;
}

// ---------------- BN stats: vectorized f16x8 loads, LDS tree, few atomics ----------------

__global__ __launch_bounds__(256) void k_colstats(const f16* __restrict__ y,
                                                  float* __restrict__ sums, int n) {
  __shared__ float sh[8][256];
  int t = threadIdx.x;
  int cg = (t & 31) * 8;  // col group of 8
  int rs = t >> 5;        // row slot 0..7
  float s[8] = {}, s2[8] = {};
  for (int r = blockIdx.x * 8 + rs; r < n; r += gridDim.x * 8) {
    f16x8 v = *(const f16x8*)(y + (size_t)r * 256 + cg);
#pragma unroll
    for (int j = 0; j < 8; ++j) {
      float f = (float)v[j];
      s[j] += f;
      s2[j] += f * f;
    }
  }
#pragma unroll
  for (int j = 0; j < 8; ++j) sh[rs][cg + j] = s[j];
  __syncthreads();
  float tot = 0.f;
#pragma unroll
  for (int k = 0; k < 8; ++k) tot += sh[k][t];
  atomicAdd(&sums[t], tot);
  __syncthreads();
#pragma unroll
  for (int j = 0; j < 8; ++j) sh[rs][cg + j] = s2[j];
  __syncthreads();
  tot = 0.f;
#pragma unroll
  for (int k = 0; k < 8; ++k) tot += sh[k][t];
  atomicAdd(&sums[256 + t], tot);
}

// bnparam also zeroes biasRow for the subsequent biasfold
__global__ void k_bnparam(const float* __restrict__ sums, float* __restrict__ scale,
                          float* __restrict__ shift, float* __restrict__ biasRow, int n) {
  int c = threadIdx.x;
  float inv = 1.0f / (float)n;
  float mean = sums[c] * inv;
  float var = sums[256 + c] * inv - mean * mean;
  float rstd = rsqrtf(var + 1e-5f);
  scale[c] = rstd;
  shift[c] = -mean * rstd;
  biasRow[c] = 0.f;
}

// ---------------- launch ----------------

extern "C" void kernel_launch(void* const* d_in, const int* in_sizes, int n_in,
                              void* d_out, int out_size, void* d_ws, size_t ws_size,
                              hipStream_t stream) {
  const float* x = (const float*)d_in[0];
  const int* ei = (const int*)d_in[1];
  const float* ew = (const float*)d_in[2];
  const float* W1 = (const float*)d_in[3];
  const float* b1 = (const float*)d_in[4];
  const float* W2 = (const float*)d_in[5];
  const float* b2 = (const float*)d_in[6];
  const float* W3 = (const float*)d_in[7];
  const float* b3 = (const float*)d_in[8];
  float* out = (float*)d_out;

  const int N = in_sizes[0] / 512;  // 100000
  const int E = in_sizes[2];        // 3200000

  char* p = (char*)d_ws;
  auto alloc = [&](size_t bytes) {
    void* r = (void*)p;
    p += (bytes + 255) & ~(size_t)255;
    return r;
  };
  int* rowptr = (int*)alloc((size_t)(N + 1) * 4);
  int* cnt = (int*)alloc((size_t)N * 4);
  int* bsum = (int*)alloc(4096);
  float* sums = (float*)alloc(512 * 4);
  float* scale = (float*)alloc(256 * 4);
  float* shift = (float*)alloc(256 * 4);
  float* biasRow = (float*)alloc(256 * 4);
  f16* Wt1 = (f16*)alloc((size_t)512 * 256 * 2);
  f16* Wt2 = (f16*)alloc((size_t)256 * 256 * 2);
  f16* Wt3 = (f16*)alloc((size_t)256 * 64 * 2);
  int2* ed = (int2*)alloc((size_t)E * 8);
  f16* sup = (f16*)alloc((size_t)N * 256 * 2);
  f16* act = (f16*)alloc((size_t)N * 256 * 2);

  const int* rows = ei;
  const int* colsIn = ei + E;

  // --- CSR build ---
  hipMemsetAsync(cnt, 0, (size_t)N * 4, stream);
  k_count<<<(E + THREADS - 1) / THREADS, THREADS, 0, stream>>>(rows, cnt, E);
  int nb = (N + 1023) / 1024;
  k_scan1<<<nb, 256, 0, stream>>>(cnt, rowptr, bsum, N);
  k_scan2<<<1, 256, 0, stream>>>(bsum, nb);
  k_scan3<<<nb, 256, 0, stream>>>(rowptr, bsum, N, E);
  hipMemsetAsync(cnt, 0, (size_t)N * 4, stream);
  k_fill<<<(E + THREADS - 1) / THREADS, THREADS, 0, stream>>>(
      rows, colsIn, ew, rowptr, cnt, ed, E);

  const int gemmBlocks = (N + 127) / 128;
  const int agg256Blocks = (N * 64 + THREADS - 1) / THREADS;
  const int agg64Blocks = (((N + 3) / 4) * 64 + THREADS - 1) / THREADS;

  // --- Layer 1: no BN on input; convW zeroes sums for colstats-L1 ---
  k_convW<<<(512 * 256 + THREADS - 1) / THREADS, THREADS, 0, stream>>>(W1, Wt1, 512, 256, sums);
  k_gemm_mfma<256, false><<<gemmBlocks, 256, 0, stream>>>(x, Wt1, nullptr, sup, N, 512);
  k_agg256<<<agg256Blocks, THREADS, 0, stream>>>(sup, rowptr, ed, b1, act, N);

  // --- BN1 + fold into W2 (convWs zeroes sums for colstats-L2) ---
  k_colstats<<<120, 256, 0, stream>>>(act, sums, N);
  k_bnparam<<<1, 256, 0, stream>>>(sums, scale, shift, biasRow, N);
  k_biasfold<<<16, 256, 0, stream>>>(shift, W2, biasRow, 256, 256);
  k_convWs<<<(256 * 256 + THREADS - 1) / THREADS, THREADS, 0, stream>>>(W2, scale, Wt2, 256, 256, sums);

  // --- Layer 2 ---
  k_gemm_mfma<256, true><<<gemmBlocks, 256, 0, stream>>>(act, Wt2, biasRow, sup, N, 256);
  k_agg256<<<agg256Blocks, THREADS, 0, stream>>>(sup, rowptr, ed, b2, act, N);

  // --- BN2 + fold into W3 ---
  k_colstats<<<120, 256, 0, stream>>>(act, sums, N);
  k_bnparam<<<1, 256, 0, stream>>>(sums, scale, shift, biasRow, N);
  k_biasfold<<<16, 256, 0, stream>>>(shift, W3, biasRow, 256, 64);
  k_convWs<<<(256 * 64 + THREADS - 1) / THREADS, THREADS, 0, stream>>>(W3, scale, Wt3, 256, 64, sums);

  // --- Layer 3 ---
  k_gemm_mfma<64, true><<<gemmBlocks, 256, 0, stream>>>(act, Wt3, biasRow, sup, N, 256);
  k_agg64<<<agg64Blocks, THREADS, 0, stream>>>(sup, rowptr, ed, b3, out, N);
}